// Round 3
// baseline (863.518 us; speedup 1.0000x reference)
//
#include <hip/hip_runtime.h>
#include <hip/hip_bf16.h>
#include <type_traits>

typedef __hip_bfloat16 bf16;
typedef __attribute__((ext_vector_type(8))) short s8v;   // 8 x bf16 (16B)
typedef __attribute__((ext_vector_type(4))) short s4v;   // 4 x bf16 (8B)
typedef __attribute__((ext_vector_type(4))) float f4v;   // MFMA C/D frag

#define MFMA16(A, B, C) __builtin_amdgcn_mfma_f32_16x16x32_bf16((A), (B), (C), 0, 0, 0)

constexpr int SEQ = 2048;
constexpr int DIM = 4096;
constexpr int NH  = 32;
constexpr int HD  = 128;

__device__ __forceinline__ short f2bs(float f) {
    __hip_bfloat16_raw r = __float2bfloat16(f);
    return (short)r.x;
}

// async global->LDS, 16B per lane. HW semantics: wave-uniform LDS base +
// lane*16; lane i's global data lands at base + i*16.
__device__ __forceinline__ void ld_g2l(const bf16* g, bf16* l) {
    __builtin_amdgcn_global_load_lds(
        (const __attribute__((address_space(1))) void*)g,
        (__attribute__((address_space(3))) void*)l, 16, 0, 0);
}

// ---------------------------------------------------------------------------
// fp32 -> bf16 elementwise convert (float4 loads)
// ---------------------------------------------------------------------------
__global__ void convert_bf16(const float* __restrict__ s, bf16* __restrict__ d) {
    int i = blockIdx.x * blockDim.x + threadIdx.x;
    float4 f = ((const float4*)s)[i];
    s4v o;
    o[0] = f2bs(f.x); o[1] = f2bs(f.y); o[2] = f2bs(f.z); o[3] = f2bs(f.w);
    *(s4v*)(d + (size_t)i * 4) = o;
}

// ---------------------------------------------------------------------------
// fp32 [R][C] -> bf16 [C][R] transpose + convert, vectorized both sides.
// 64x64 tile, 256 threads. Loads: float4 (fully coalesced). Stores: s8v 16B
// (each thread writes 8 consecutive output elems = 8 source rows, same col).
// LDS [64][65] f32: read gather t[rr+e][oc] is 2-lanes/bank (free, m136).
// ---------------------------------------------------------------------------
__global__ __launch_bounds__(256) void convt_bf16(const float* __restrict__ src,
                                                  bf16* __restrict__ dst,
                                                  int R, int C) {
    __shared__ float t[64][65];
    const int c0 = blockIdx.x * 64, r0 = blockIdx.y * 64;
    const int tid = threadIdx.x;
    const int lr = tid >> 4;             // 0..15
    const int lc = (tid & 15) * 4;       // 0..60
#pragma unroll
    for (int i = 0; i < 4; i++) {
        float4 f = *(const float4*)(src + (size_t)(r0 + lr + 16 * i) * C + c0 + lc);
        t[lr + 16 * i][lc]     = f.x;
        t[lr + 16 * i][lc + 1] = f.y;
        t[lr + 16 * i][lc + 2] = f.z;
        t[lr + 16 * i][lc + 3] = f.w;
    }
    __syncthreads();
    const int oc = tid >> 2;             // output row (source col) 0..63
#pragma unroll
    for (int i = 0; i < 2; i++) {
        int rr = (tid & 3) * 8 + 32 * i; // 0..56 step 8
        s8v o;
#pragma unroll
        for (int e = 0; e < 8; e++) o[e] = f2bs(t[rr + e][oc]);
        *(s8v*)(dst + (size_t)(c0 + oc) * R + r0 + rr) = o;
    }
}

// ---------------------------------------------------------------------------
// 3-buffer GEMM: C[M,N] = A[M,K] * Bt[N,K]^T, bf16 in, CT out.
//   BM=128, BN=256, BK=64, 512 threads = 8 waves (2 M x 4 N), per-wave 64x64.
//   LDS 144KB: As[3][128][64] + Bs[3][256][64], triple-buffered.
//
// Why 3 buffers: stage of tile t+2 goes to buf[(t+2)%3], which is NEVER the
// buffer being read (t%3) nor the next (t+1)%3 -> no stage-overwrite hazard
// -> ONE barrier + ONE counted vmcnt per K-tile (vs 8 barriers in R2).
//
// Hazard proof:
//  * stage(t+2) issued at iter t start overwrites buf last read at iter t-1;
//    every wave's iter-(t-1) ds_reads completed before its own lgkmcnt(0)
//    (pre-MFMA), which precedes its arrival at the iter-(t-1) end barrier;
//    stage(t+2) is issued after that barrier -> all reads complete. SAFE.
//  * reads(t) at iter t see staged data: wave X staged its slice of t at
//    iter t-2 (6 loads). At iter t-1 end, X waits vmcnt(6); outstanding can
//    only be {t's 6, t+1's 6}; vmcnt retires in order -> waiting to <=6
//    retires all of t's. Barrier then publishes across waves. SAFE.
//
// Bank-conflict swizzle (unchanged from R2, verified): 16B-group
//   g=(byte>>4)&7 stored at slot g = gl ^ (row&7); global_load_lds keeps a
//   LINEAR LDS dest and the permutation is applied to the per-lane GLOBAL
//   source (rule #21); reads XOR the same term -> 2 lanes/bank (free).
// ---------------------------------------------------------------------------
template <typename CT>
__global__ __launch_bounds__(512, 2) void gemm_3b(const bf16* __restrict__ A,
                                                  const bf16* __restrict__ Bt,
                                                  CT* __restrict__ C,
                                                  int M, int N, int K) {
    __shared__ bf16 As_[3][128 * 64];
    __shared__ bf16 Bs_[3][256 * 64];
    const int tid  = threadIdx.x;
    const int lane = tid & 63;
    const int wv   = tid >> 6;
    const int m16  = lane & 15;
    const int quad = lane >> 4;
    const int wm   = wv >> 2, wn = wv & 3;
    const int bm   = blockIdx.y, bn = blockIdx.x;

    const bf16* Ab = A  + (size_t)bm * 128 * K;
    const bf16* Bb = Bt + (size_t)bn * 256 * K;

    // staging geometry: unit = 128 rows x 64 cols = 16KB = 2 loads/thread
    const int i0   = wv * 64 + lane;          // slot for load l=0
    const int row0 = i0 >> 3;                 // 0..63 (l=1 adds 64; row&7 same)
    const int gc8  = ((i0 & 7) ^ (row0 & 7)) * 8;   // swizzled source group
    const int dst0 = (wv * 64) * 8;           // wave-uniform dest (+lane*16B)
    const int dst1 = (512 + wv * 64) * 8;

    // read geometry
    const int aB = (wm * 64 + m16) * 64;
    const int bB = (wn * 64 + m16) * 64;
    const int swz = m16 & 7;
    const int c0k = ((0 + quad) ^ swz) * 8;   // ks=0 col offset (bf16 units)
    const int c1k = ((4 + quad) ^ swz) * 8;   // ks=1

    const int NT = K >> 6;

    f4v acc[4][4] = {};
    s8v aR[4][2], bR[4][2];

#define STAGEU(gb, lb) do { \
        ld_g2l((gb) + (size_t)row0 * K + gc8, (lb) + dst0); \
        ld_g2l((gb) + (size_t)(row0 + 64) * K + gc8, (lb) + dst1); } while (0)
#define LDA_(i, ks) aR[i][ks] = *(const s8v*)(Ac + aB + (i) * 1024 + ((ks) ? c1k : c0k))
#define LDB_(j, ks) bR[j][ks] = *(const s8v*)(Bc + bB + (j) * 1024 + ((ks) ? c1k : c0k))
#define MMQ(i, j) do { acc[i][j] = MFMA16(aR[i][0], bR[j][0], acc[i][j]); \
                       acc[i][j] = MFMA16(aR[i][1], bR[j][1], acc[i][j]); } while (0)
#define LGKM0() do { asm volatile("s_waitcnt lgkmcnt(0)" ::: "memory"); \
                     __builtin_amdgcn_sched_barrier(0); } while (0)

    // ---- prologue: stage t0 and t1 (6 loads each); wait t0 landed ----
    STAGEU(Ab, As_[0]);
    STAGEU(Bb, Bs_[0]);
    STAGEU(Bb + (size_t)128 * K, Bs_[0] + 128 * 64);
    if (NT > 1) {
        STAGEU(Ab + 64, As_[1]);
        STAGEU(Bb + 64, Bs_[1]);
        STAGEU(Bb + (size_t)128 * K + 64, Bs_[1] + 128 * 64);
        asm volatile("s_waitcnt vmcnt(6)" ::: "memory");
    } else {
        asm volatile("s_waitcnt vmcnt(0)" ::: "memory");
    }
    __builtin_amdgcn_sched_barrier(0);
    __builtin_amdgcn_s_barrier();

    int cur = 0, nx2 = 2;   // t%3 and (t+2)%3 tracked without division
    for (int t = 0; t < NT; ++t) {
        const bf16* Ac = As_[cur];
        const bf16* Bc = Bs_[cur];
        const bool more = (t + 2 < NT);

        // ---- stage tile t+2 into buf[(t+2)%3] (issue early, 6 loads) ----
        if (more) {
            const int k2 = (t + 2) << 6;
            bf16* Ad = As_[nx2];
            bf16* Bd = Bs_[nx2];
            STAGEU(Ab + k2, Ad);
            STAGEU(Bb + k2, Bd);
            STAGEU(Bb + (size_t)128 * K + k2, Bd + 128 * 64);
        }

        // ---- fragment reads (16 x ds_read_b128) ----
        LDA_(0, 0); LDA_(0, 1); LDA_(1, 0); LDA_(1, 1);
        LDA_(2, 0); LDA_(2, 1); LDA_(3, 0); LDA_(3, 1);
        LDB_(0, 0); LDB_(0, 1); LDB_(1, 0); LDB_(1, 1);
        LDB_(2, 0); LDB_(2, 1); LDB_(3, 0); LDB_(3, 1);
        LGKM0();

        // ---- 32 MFMA ----
        __builtin_amdgcn_s_setprio(1);
        MMQ(0, 0); MMQ(0, 1); MMQ(0, 2); MMQ(0, 3);
        MMQ(1, 0); MMQ(1, 1); MMQ(1, 2); MMQ(1, 3);
        MMQ(2, 0); MMQ(2, 1); MMQ(2, 2); MMQ(2, 3);
        MMQ(3, 0); MMQ(3, 1); MMQ(3, 2); MMQ(3, 3);
        __builtin_amdgcn_s_setprio(0);

        // ---- ensure t+1 landed (counted: t+2's 6 may stay in flight) ----
        if (more) asm volatile("s_waitcnt vmcnt(6)" ::: "memory");
        else      asm volatile("s_waitcnt vmcnt(0)" ::: "memory");
        __builtin_amdgcn_sched_barrier(0);
        __builtin_amdgcn_s_barrier();

        cur = (cur == 2) ? 0 : cur + 1;
        nx2 = (nx2 == 2) ? 0 : nx2 + 1;
    }

#undef STAGEU
#undef LDA_
#undef LDB_
#undef MMQ
#undef LGKM0

#pragma unroll
    for (int i = 0; i < 4; i++)
#pragma unroll
        for (int j = 0; j < 4; j++)
#pragma unroll
            for (int r = 0; r < 4; r++) {
                int row = bm * 128 + wm * 64 + i * 16 + quad * 4 + r;
                int col = bn * 256 + wn * 64 + j * 16 + m16;
                if constexpr (std::is_same<CT, float>::value)
                    C[(size_t)row * N + col] = acc[i][j][r];
                else
                    C[(size_t)row * N + col] = __float2bfloat16(acc[i][j][r]);
            }
}

// ---------------------------------------------------------------------------
// Fallback GEMM (fp32 B with in-loop conversion) — used only if ws_size is
// too small for the bf16-conversion buffers.
// ---------------------------------------------------------------------------
template <typename AT, typename CT>
__global__ __launch_bounds__(256) void gemm_nat(const AT* __restrict__ A,
                                                const float* __restrict__ B,
                                                CT* __restrict__ C,
                                                int M, int N, int K) {
    __shared__ short As[128][40];
    __shared__ short Bs[128][40];
    const int tid  = threadIdx.x;
    const int lane = tid & 63;
    const int w    = tid >> 6;
    const int m16  = lane & 15;
    const int quad = lane >> 4;
    const int wm   = w >> 1, wn = w & 1;
    const int bm   = blockIdx.y, bn = blockIdx.x;

    const AT* Ab = A + (size_t)bm * 128 * K;

    f4v acc[4][4] = {};
    const int r0 = tid >> 2;
    const int kc = (tid & 3) * 8;

    for (int k0 = 0; k0 < K; k0 += 32) {
        if constexpr (std::is_same<AT, float>::value) {
#pragma unroll
            for (int half = 0; half < 2; half++) {
                const float* src = Ab + (size_t)(r0 + 64 * half) * K + k0 + kc;
                float4 f0 = *(const float4*)(src);
                float4 f1 = *(const float4*)(src + 4);
                s8v t;
                t[0] = f2bs(f0.x); t[1] = f2bs(f0.y); t[2] = f2bs(f0.z); t[3] = f2bs(f0.w);
                t[4] = f2bs(f1.x); t[5] = f2bs(f1.y); t[6] = f2bs(f1.z); t[7] = f2bs(f1.w);
                *(s8v*)&As[r0 + 64 * half][kc] = t;
            }
        } else {
            *(s8v*)&As[r0][kc]      = *(const s8v*)(Ab + (size_t)r0 * K + k0 + kc);
            *(s8v*)&As[r0 + 64][kc] = *(const s8v*)(Ab + (size_t)(r0 + 64) * K + k0 + kc);
        }
#pragma unroll
        for (int v = tid; v < 512; v += 256) {
            int kr = v >> 4;
            int nc = (v & 15) * 8;
            const float* src = B + (size_t)(k0 + kr) * N + bn * 128 + nc;
            float4 f0 = *(const float4*)(src);
            float4 f1 = *(const float4*)(src + 4);
            Bs[nc + 0][kr] = f2bs(f0.x); Bs[nc + 1][kr] = f2bs(f0.y);
            Bs[nc + 2][kr] = f2bs(f0.z); Bs[nc + 3][kr] = f2bs(f0.w);
            Bs[nc + 4][kr] = f2bs(f1.x); Bs[nc + 5][kr] = f2bs(f1.y);
            Bs[nc + 6][kr] = f2bs(f1.z); Bs[nc + 7][kr] = f2bs(f1.w);
        }
        __syncthreads();

        s8v a[4], b[4];
#pragma unroll
        for (int i = 0; i < 4; i++) a[i] = *(s8v*)&As[wm * 64 + i * 16 + m16][quad * 8];
#pragma unroll
        for (int j = 0; j < 4; j++) b[j] = *(s8v*)&Bs[wn * 64 + j * 16 + m16][quad * 8];
#pragma unroll
        for (int i = 0; i < 4; i++)
#pragma unroll
            for (int j = 0; j < 4; j++) acc[i][j] = MFMA16(a[i], b[j], acc[i][j]);
        __syncthreads();
    }

#pragma unroll
    for (int i = 0; i < 4; i++)
#pragma unroll
        for (int j = 0; j < 4; j++)
#pragma unroll
            for (int r = 0; r < 4; r++) {
                int row = bm * 128 + wm * 64 + i * 16 + quad * 4 + r;
                int col = bn * 128 + wn * 64 + j * 16 + m16;
                if constexpr (std::is_same<CT, float>::value)
                    C[(size_t)row * N + col] = acc[i][j][r];
                else
                    C[(size_t)row * N + col] = __float2bfloat16(acc[i][j][r]);
            }
}

// ---------------------------------------------------------------------------
// RoPE in-place on bf16 Q and K; freqs fp32.
// ---------------------------------------------------------------------------
__global__ void rope_kernel(bf16* __restrict__ Q, bf16* __restrict__ K,
                            const float* __restrict__ fc, const float* __restrict__ fs) {
    int tid = blockIdx.x * blockDim.x + threadIdx.x;
    int s = tid >> 11;
    int r = tid & 2047;
    int i = r & 63;
    float c  = fc[s * 64 + i];
    float sn = fs[s * 64 + i];
    size_t idx = (size_t)s * DIM + 2 * r;
    float qre = __bfloat162float(Q[idx]), qim = __bfloat162float(Q[idx + 1]);
    Q[idx]     = __float2bfloat16(qre * c - qim * sn);
    Q[idx + 1] = __float2bfloat16(qre * sn + qim * c);
    float kre = __bfloat162float(K[idx]), kim = __bfloat162float(K[idx + 1]);
    K[idx]     = __float2bfloat16(kre * c - kim * sn);
    K[idx + 1] = __float2bfloat16(kre * sn + kim * c);
}

// ---------------------------------------------------------------------------
// Flash attention (causal). Grid: (32 qb-blocks DESCENDING, 32 heads).
// Unchanged from round 1 (coalesced V staging + reg prefetch + 2 barriers).
// ---------------------------------------------------------------------------
__global__ __launch_bounds__(256) void attn_kernel(const bf16* __restrict__ Q,
                                                   const bf16* __restrict__ K,
                                                   const bf16* __restrict__ V,
                                                   bf16* __restrict__ O) {
    __shared__ short Ks[64][136];
    __shared__ short Vs[128][72];
    __shared__ short Ps[64][72];

    const int qb = (int)gridDim.x - 1 - (int)blockIdx.x;   // long blocks first
    const int h  = blockIdx.y;
    const int tid  = threadIdx.x;
    const int w    = tid >> 6;
    const int lane = tid & 63;
    const int m16  = lane & 15;
    const int quad = lane >> 4;
    const float scale = 0.08838834764831845f;   // 1/sqrt(128)

    const int rn  = tid >> 4;            // 0..15
    const int rc  = (tid & 15) * 8;      // 0,8,...,120
    const int dcs = (tid & 15) & 7;      // = (rc>>3)&7, V write swizzle term

    s8v aq[4];
    {
        const bf16* qp = Q + (size_t)(qb * 64 + w * 16 + m16) * DIM + h * HD + quad * 8;
#pragma unroll
        for (int ks = 0; ks < 4; ks++) aq[ks] = *(const s8v*)(qp + ks * 32);
    }

    f4v acc[8] = {};
    float mrow[4] = {-1e30f, -1e30f, -1e30f, -1e30f};
    float lrow[4] = {};

    s8v kreg[4], vreg[4];
    {
        const bf16* kp = K + (size_t)rn * DIM + h * HD + rc;
        const bf16* vp = V + (size_t)rn * DIM + h * HD + rc;
#pragma unroll
        for (int it = 0; it < 4; it++) {
            kreg[it] = *(const s8v*)(kp + (size_t)it * 16 * DIM);
            vreg[it] = *(const s8v*)(vp + (size_t)it * 16 * DIM);
        }
    }

    for (int kt = 0; kt <= qb; kt++) {
        // ---- stage regs -> LDS (K direct; V transposed w/ XOR swizzle) ----
#pragma unroll
        for (int it = 0; it < 4; it++)
            *(s8v*)&Ks[it * 16 + rn][rc] = kreg[it];
#pragma unroll
        for (int it = 0; it < 4; it++) {
            int n   = it * 16 + rn;                       // key index 0..63
            int col = (((n >> 3) ^ dcs) << 3) | (n & 7);  // swizzled column
#pragma unroll
            for (int e = 0; e < 8; e++) Vs[rc + e][col] = vreg[it][e];
        }
        __syncthreads();

        // ---- prefetch tile kt+1 ----
        if (kt < qb) {
            const bf16* kp = K + (size_t)((kt + 1) * 64 + rn) * DIM + h * HD + rc;
            const bf16* vp = V + (size_t)((kt + 1) * 64 + rn) * DIM + h * HD + rc;
#pragma unroll
            for (int it = 0; it < 4; it++) {
                kreg[it] = *(const s8v*)(kp + (size_t)it * 16 * DIM);
                vreg[it] = *(const s8v*)(vp + (size_t)it * 16 * DIM);
            }
        }

        // ---- QK^T ----
        f4v sc[4] = {};
#pragma unroll
        for (int j = 0; j < 4; j++)
#pragma unroll
            for (int ks = 0; ks < 4; ks++) {
                s8v bk = *(s8v*)&Ks[j * 16 + m16][ks * 32 + quad * 8];
                sc[j] = MFMA16(aq[ks], bk, sc[j]);
            }

        const bool diag = (kt == qb);
#pragma unroll
        for (int j = 0; j < 4; j++)
#pragma unroll
            for (int r = 0; r < 4; r++) {
                float sv = sc[j][r] * scale;
                if (diag && (j * 16 + m16) > (w * 16 + quad * 4 + r)) sv = -1e30f;
                sc[j][r] = sv;
            }

        // ---- online softmax ----
#pragma unroll
        for (int r = 0; r < 4; r++) {
            float mx = fmaxf(fmaxf(sc[0][r], sc[1][r]), fmaxf(sc[2][r], sc[3][r]));
#pragma unroll
            for (int off = 1; off < 16; off <<= 1) mx = fmaxf(mx, __shfl_xor(mx, off, 64));
            float mn    = fmaxf(mrow[r], mx);
            float alpha = __expf(mrow[r] - mn);
            mrow[r] = mn;
            float rs = 0.f;
#pragma unroll
            for (int j = 0; j < 4; j++) {
                float p = __expf(sc[j][r] - mn);
                sc[j][r] = p;
                rs += p;
            }
#pragma unroll
            for (int off = 1; off < 16; off <<= 1) rs += __shfl_xor(rs, off, 64);
            lrow[r] = lrow[r] * alpha + rs;
#pragma unroll
            for (int jo = 0; jo < 8; jo++) acc[jo][r] = acc[jo][r] * alpha;
        }

        // ---- P store (wave-private rows -> no block barrier needed) ----
#pragma unroll
        for (int j = 0; j < 4; j++)
#pragma unroll
            for (int r = 0; r < 4; r++)
                Ps[w * 16 + quad * 4 + r][j * 16 + m16] = f2bs(sc[j][r]);
        asm volatile("s_waitcnt lgkmcnt(0)" ::: "memory");
        __builtin_amdgcn_sched_barrier(0);

        // ---- PV (Vs read through the same XOR swizzle) ----
#pragma unroll
        for (int ks2 = 0; ks2 < 2; ks2++) {
            s8v ap = *(s8v*)&Ps[w * 16 + m16][ks2 * 32 + quad * 8];
#pragma unroll
            for (int jo = 0; jo < 8; jo++) {
                int dv = jo * 16 + m16;
                int cg = (((ks2 * 4 + quad) ^ ((dv >> 3) & 7)) << 3);
                s8v bv = *(s8v*)&Vs[dv][cg];
                acc[jo] = MFMA16(ap, bv, acc[jo]);
            }
        }
        __syncthreads();
    }

#pragma unroll
    for (int jo = 0; jo < 8; jo++)
#pragma unroll
        for (int r = 0; r < 4; r++) {
            float o = acc[jo][r] / fmaxf(lrow[r], 1e-30f);
            int row = qb * 64 + w * 16 + quad * 4 + r;
            int col = h * HD + jo * 16 + m16;
            O[(size_t)row * DIM + col] = __float2bfloat16(o);
        }
}

// ---------------------------------------------------------------------------
extern "C" void kernel_launch(void* const* d_in, const int* in_sizes, int n_in,
                              void* d_out, int out_size, void* d_ws, size_t ws_size,
                              hipStream_t stream) {
    const float* x  = (const float*)d_in[0];
    const float* wq = (const float*)d_in[1];
    const float* wk = (const float*)d_in[2];
    const float* wv = (const float*)d_in[3];
    const float* wo = (const float*)d_in[4];
    const float* fc = (const float*)d_in[5];
    const float* fs = (const float*)d_in[6];

    float* out = (float*)d_out;

    const size_t SZ = (size_t)SEQ * DIM;
    const size_t WZ = (size_t)DIM * DIM;
    bf16* Q  = (bf16*)d_ws;
    bf16* Kb = Q + SZ;
    bf16* V  = Kb + SZ;
    bf16* AO = V + SZ;

    const size_t need = (5 * SZ + WZ) * sizeof(bf16);   // 112 MB

    if (ws_size >= need) {
        bf16* xb = AO + SZ;        // [SEQ][DIM] bf16
        bf16* wb = xb + SZ;        // [DIM][DIM] bf16, transposed weight, reused

        dim3 tGw(DIM / 64, DIM / 64);
        dim3 gG8(DIM / 256, SEQ / 128);     // (16, 16) = 256 blocks

        convert_bf16<<<(int)(SZ / 4 / 256), 256, 0, stream>>>(x, xb);

        convt_bf16<<<tGw, 256, 0, stream>>>(wq, wb, DIM, DIM);
        gemm_3b<bf16><<<gG8, 512, 0, stream>>>(xb, wb, Q, SEQ, DIM, DIM);
        convt_bf16<<<tGw, 256, 0, stream>>>(wk, wb, DIM, DIM);
        gemm_3b<bf16><<<gG8, 512, 0, stream>>>(xb, wb, Kb, SEQ, DIM, DIM);
        convt_bf16<<<tGw, 256, 0, stream>>>(wv, wb, DIM, DIM);
        gemm_3b<bf16><<<gG8, 512, 0, stream>>>(xb, wb, V, SEQ, DIM, DIM);

        rope_kernel<<<(SEQ * (DIM / 2)) / 256, 256, 0, stream>>>(Q, Kb, fc, fs);
        attn_kernel<<<dim3(SEQ / 64, NH), 256, 0, stream>>>(Q, Kb, V, AO);

        convt_bf16<<<tGw, 256, 0, stream>>>(wo, wb, DIM, DIM);
        gemm_3b<float><<<gG8, 512, 0, stream>>>(AO, wb, out, SEQ, DIM, DIM);
    } else {
        dim3 gGn(DIM / 128, SEQ / 128);
        gemm_nat<float, bf16><<<gGn, 256, 0, stream>>>(x, wq, Q,  SEQ, DIM, DIM);
        gemm_nat<float, bf16><<<gGn, 256, 0, stream>>>(x, wk, Kb, SEQ, DIM, DIM);
        gemm_nat<float, bf16><<<gGn, 256, 0, stream>>>(x, wv, V,  SEQ, DIM, DIM);
        rope_kernel<<<(SEQ * (DIM / 2)) / 256, 256, 0, stream>>>(Q, Kb, fc, fs);
        attn_kernel<<<dim3(SEQ / 64, NH), 256, 0, stream>>>(Q, Kb, V, AO);
        gemm_nat<bf16, float><<<gGn, 256, 0, stream>>>(AO, wo, out, SEQ, DIM, DIM);
    }
}

// Round 4
// 752.894 us; speedup vs baseline: 1.1469x; 1.1469x over previous
//
#include <hip/hip_runtime.h>
#include <hip/hip_bf16.h>
#include <type_traits>

typedef __hip_bfloat16 bf16;
typedef __attribute__((ext_vector_type(8))) short s8v;   // 8 x bf16 (16B)
typedef __attribute__((ext_vector_type(4))) short s4v;   // 4 x bf16 (8B)
typedef __attribute__((ext_vector_type(4))) float f4v;   // MFMA C/D frag

#define MFMA16(A, B, C) __builtin_amdgcn_mfma_f32_16x16x32_bf16((A), (B), (C), 0, 0, 0)

constexpr int SEQ = 2048;
constexpr int DIM = 4096;
constexpr int NH  = 32;
constexpr int HD  = 128;

__device__ __forceinline__ short f2bs(float f) {
    __hip_bfloat16_raw r = __float2bfloat16(f);
    return (short)r.x;
}

// async global->LDS, 16B per lane. HW semantics: wave-uniform LDS base +
// lane*16; lane i's global data lands at base + i*16.
__device__ __forceinline__ void ld_g2l(const bf16* g, bf16* l) {
    __builtin_amdgcn_global_load_lds(
        (const __attribute__((address_space(1))) void*)g,
        (__attribute__((address_space(3))) void*)l, 16, 0, 0);
}

// ---------------------------------------------------------------------------
// fp32 -> bf16 elementwise convert (float4 loads)
// ---------------------------------------------------------------------------
__global__ void convert_bf16(const float* __restrict__ s, bf16* __restrict__ d) {
    int i = blockIdx.x * blockDim.x + threadIdx.x;
    float4 f = ((const float4*)s)[i];
    s4v o;
    o[0] = f2bs(f.x); o[1] = f2bs(f.y); o[2] = f2bs(f.z); o[3] = f2bs(f.w);
    *(s4v*)(d + (size_t)i * 4) = o;
}

// ---------------------------------------------------------------------------
// fp32 [R][C] -> bf16 [C][R] transpose + convert, vectorized both sides.
// 64x64 tile, 256 threads. Loads: float4 (fully coalesced). Stores: s8v 16B.
// LDS [64][65] f32: read gather t[rr+e][oc] is 2-lanes/bank (free, m136).
// ---------------------------------------------------------------------------
__global__ __launch_bounds__(256) void convt_bf16(const float* __restrict__ src,
                                                  bf16* __restrict__ dst,
                                                  int R, int C) {
    __shared__ float t[64][65];
    const int c0 = blockIdx.x * 64, r0 = blockIdx.y * 64;
    const int tid = threadIdx.x;
    const int lr = tid >> 4;             // 0..15
    const int lc = (tid & 15) * 4;       // 0..60
#pragma unroll
    for (int i = 0; i < 4; i++) {
        float4 f = *(const float4*)(src + (size_t)(r0 + lr + 16 * i) * C + c0 + lc);
        t[lr + 16 * i][lc]     = f.x;
        t[lr + 16 * i][lc + 1] = f.y;
        t[lr + 16 * i][lc + 2] = f.z;
        t[lr + 16 * i][lc + 3] = f.w;
    }
    __syncthreads();
    const int oc = tid >> 2;             // output row (source col) 0..63
#pragma unroll
    for (int i = 0; i < 2; i++) {
        int rr = (tid & 3) * 8 + 32 * i; // 0..56 step 8
        s8v o;
#pragma unroll
        for (int e = 0; e < 8; e++) o[e] = f2bs(t[rr + e][oc]);
        *(s8v*)(dst + (size_t)(c0 + oc) * R + r0 + rr) = o;
    }
}

// ---------------------------------------------------------------------------
// 8-phase GEMM (measured-best R2 schedule) + XCD-aware bijective swizzle.
//   C[M,N] = A[M,K] * Bt[N,K]^T, bf16 in, CT out.
//   BM=128, BN=256, BK=64, 512 threads = 8 waves (2 M x 4 N), per-wave 64x64.
//   LDS 96KB: As[2][128][64] + Bs[2][256][64], double-buffered per K-tile.
//
// XCD swizzle (grid MUST be 16x16): v = by*16+bx; XCD j = v%8 gets slots
// s = v/8 (0..31) mapped to bn = 2j + s/16, bm = s%16  -> each XCD owns 2
// bn-columns: its 16 co-resident blocks share a 2MB B-panel (L2-fits, 4MB)
// -> B HBM traffic ~32MB total instead of ~256MB. Bijective (j,s) <-> v.
//
// Bank-conflict swizzle (verified R2/R3): 16B-group g=(byte>>4)&7 stored at
// slot g = gl ^ (row&7); global_load_lds keeps a LINEAR LDS dest and the
// permutation is applied to the per-lane GLOBAL source (rule #21); reads
// XOR the same term -> 2 lanes/bank (free).
//
// Schedule per K-tile t (computing buf cur=t&1), quadrant order
//   (i01,j01),(i01,j23),(i23,j01),(i23,j23), 8 MFMA each; stages of tile
//   t+2 split across ph3 (B) / ph4 (A); vmcnt(6) only at ph4.
// ---------------------------------------------------------------------------
template <typename CT>
__global__ __launch_bounds__(512, 2) void gemm_8p(const bf16* __restrict__ A,
                                                  const bf16* __restrict__ Bt,
                                                  CT* __restrict__ C,
                                                  int M, int N, int K) {
    __shared__ bf16 As_[2][128 * 64];
    __shared__ bf16 Bs_[2][256 * 64];
    const int tid  = threadIdx.x;
    const int lane = tid & 63;
    const int wv   = tid >> 6;
    const int m16  = lane & 15;
    const int quad = lane >> 4;
    const int wm   = wv >> 2, wn = wv & 3;

    // ---- XCD-aware remap (valid for 16x16 grid only; fast path only) ----
    const int v   = (int)(blockIdx.y * gridDim.x + blockIdx.x);
    const int s_  = v >> 3;
    const int bn  = (v & 7) * 2 + (s_ >> 4);
    const int bm  = s_ & 15;

    const bf16* Ab = A  + (size_t)bm * 128 * K;
    const bf16* Bb = Bt + (size_t)bn * 256 * K;

    // staging geometry: unit = 128 rows x 64 cols = 16KB = 2 loads/thread
    const int i0   = wv * 64 + lane;          // slot for load l=0
    const int row0 = i0 >> 3;                 // 0..63 (l=1 adds 64; row&7 same)
    const int gc8  = ((i0 & 7) ^ (row0 & 7)) * 8;   // swizzled source group
    const int dst0 = (wv * 64) * 8;           // wave-uniform dest (+lane*16B)
    const int dst1 = (512 + wv * 64) * 8;

    // read geometry
    const int aB = (wm * 64 + m16) * 64;
    const int bB = (wn * 64 + m16) * 64;
    const int swz = m16 & 7;
    const int c0k = ((0 + quad) ^ swz) * 8;   // ks=0 col offset (bf16 units)
    const int c1k = ((4 + quad) ^ swz) * 8;   // ks=1

    const int NT = K >> 6;

    f4v acc[4][4] = {};
    s8v aR[4][2], bR[4][2];

#define STAGEU(gb, lb) do { \
        ld_g2l((gb) + (size_t)row0 * K + gc8, (lb) + dst0); \
        ld_g2l((gb) + (size_t)(row0 + 64) * K + gc8, (lb) + dst1); } while (0)
#define LDA_(i, ks) aR[i][ks] = *(const s8v*)(Ac + aB + (i) * 1024 + ((ks) ? c1k : c0k))
#define LDB_(j, ks) bR[j][ks] = *(const s8v*)(Bc + bB + (j) * 1024 + ((ks) ? c1k : c0k))
#define MMQ(i, j) do { acc[i][j] = MFMA16(aR[i][0], bR[j][0], acc[i][j]); \
                       acc[i][j] = MFMA16(aR[i][1], bR[j][1], acc[i][j]); } while (0)
#define BARX()  __builtin_amdgcn_s_barrier()
#define LGKM0() do { asm volatile("s_waitcnt lgkmcnt(0)" ::: "memory"); \
                     __builtin_amdgcn_sched_barrier(0); } while (0)

    // ---- prologue: t0 {A,B0,B1}, t1 {B0,B1,A}; wait t0 landed ----
    STAGEU(Ab, As_[0]);
    STAGEU(Bb, Bs_[0]);
    STAGEU(Bb + (size_t)128 * K, Bs_[0] + 128 * 64);
    if (NT > 1) {
        STAGEU(Bb + 64, Bs_[1]);
        STAGEU(Bb + (size_t)128 * K + 64, Bs_[1] + 128 * 64);
        STAGEU(Ab + 64, As_[1]);
        asm volatile("s_waitcnt vmcnt(6)" ::: "memory");
    } else {
        asm volatile("s_waitcnt vmcnt(0)" ::: "memory");
    }
    __builtin_amdgcn_sched_barrier(0);
    BARX();

    for (int t = 0; t < NT; ++t) {
        const int cur = t & 1;
        const bf16* Ac = As_[cur];
        const bf16* Bc = Bs_[cur];
        const bool more = (t + 2 < NT);
        const int k2 = (t + 2) << 6;

        // ---------------- phase 1 ----------------
        LDA_(0, 0); LDA_(0, 1); LDA_(1, 0); LDA_(1, 1);
        LDB_(0, 0); LDB_(0, 1); LDB_(1, 0); LDB_(1, 1);
        BARX(); LGKM0();
        __builtin_amdgcn_s_setprio(1);
        MMQ(0, 0); MMQ(0, 1); MMQ(1, 0); MMQ(1, 1);
        __builtin_amdgcn_s_setprio(0);
        BARX();

        // ---------------- phase 2 ----------------
        LDB_(2, 0); LDB_(2, 1); LDB_(3, 0); LDB_(3, 1);
        BARX(); LGKM0();
        __builtin_amdgcn_s_setprio(1);
        MMQ(0, 2); MMQ(0, 3); MMQ(1, 2); MMQ(1, 3);
        __builtin_amdgcn_s_setprio(0);
        BARX();

        // ---------------- phase 3 ----------------
        LDA_(2, 0); LDA_(2, 1); LDA_(3, 0); LDA_(3, 1);
        if (more) {
            STAGEU(Bb + k2, Bs_[cur]);
            STAGEU(Bb + (size_t)128 * K + k2, Bs_[cur] + 128 * 64);
        }
        BARX(); LGKM0();
        __builtin_amdgcn_s_setprio(1);
        MMQ(2, 0); MMQ(2, 1); MMQ(3, 0); MMQ(3, 1);
        __builtin_amdgcn_s_setprio(0);
        BARX();

        // ---------------- phase 4 ----------------
        if (more) {
            STAGEU(Ab + k2, As_[cur]);
            asm volatile("s_waitcnt vmcnt(6)" ::: "memory");
        } else {
            asm volatile("s_waitcnt vmcnt(0)" ::: "memory");
        }
        __builtin_amdgcn_sched_barrier(0);
        BARX();
        __builtin_amdgcn_s_setprio(1);
        MMQ(2, 2); MMQ(2, 3); MMQ(3, 2); MMQ(3, 3);
        __builtin_amdgcn_s_setprio(0);
        BARX();
    }

#undef STAGEU
#undef LDA_
#undef LDB_
#undef MMQ
#undef BARX
#undef LGKM0

#pragma unroll
    for (int i = 0; i < 4; i++)
#pragma unroll
        for (int j = 0; j < 4; j++)
#pragma unroll
            for (int r = 0; r < 4; r++) {
                int row = bm * 128 + wm * 64 + i * 16 + quad * 4 + r;
                int col = bn * 256 + wn * 64 + j * 16 + m16;
                if constexpr (std::is_same<CT, float>::value)
                    C[(size_t)row * N + col] = acc[i][j][r];
                else
                    C[(size_t)row * N + col] = __float2bfloat16(acc[i][j][r]);
            }
}

// ---------------------------------------------------------------------------
// Fallback GEMM (fp32 B with in-loop conversion) — used only if ws_size is
// too small for the bf16-conversion buffers.
// ---------------------------------------------------------------------------
template <typename AT, typename CT>
__global__ __launch_bounds__(256) void gemm_nat(const AT* __restrict__ A,
                                                const float* __restrict__ B,
                                                CT* __restrict__ C,
                                                int M, int N, int K) {
    __shared__ short As[128][40];
    __shared__ short Bs[128][40];
    const int tid  = threadIdx.x;
    const int lane = tid & 63;
    const int w    = tid >> 6;
    const int m16  = lane & 15;
    const int quad = lane >> 4;
    const int wm   = w >> 1, wn = w & 1;
    const int bm   = blockIdx.y, bn = blockIdx.x;

    const AT* Ab = A + (size_t)bm * 128 * K;

    f4v acc[4][4] = {};
    const int r0 = tid >> 2;
    const int kc = (tid & 3) * 8;

    for (int k0 = 0; k0 < K; k0 += 32) {
        if constexpr (std::is_same<AT, float>::value) {
#pragma unroll
            for (int half = 0; half < 2; half++) {
                const float* src = Ab + (size_t)(r0 + 64 * half) * K + k0 + kc;
                float4 f0 = *(const float4*)(src);
                float4 f1 = *(const float4*)(src + 4);
                s8v t;
                t[0] = f2bs(f0.x); t[1] = f2bs(f0.y); t[2] = f2bs(f0.z); t[3] = f2bs(f0.w);
                t[4] = f2bs(f1.x); t[5] = f2bs(f1.y); t[6] = f2bs(f1.z); t[7] = f2bs(f1.w);
                *(s8v*)&As[r0 + 64 * half][kc] = t;
            }
        } else {
            *(s8v*)&As[r0][kc]      = *(const s8v*)(Ab + (size_t)r0 * K + k0 + kc);
            *(s8v*)&As[r0 + 64][kc] = *(const s8v*)(Ab + (size_t)(r0 + 64) * K + k0 + kc);
        }
#pragma unroll
        for (int v = tid; v < 512; v += 256) {
            int kr = v >> 4;
            int nc = (v & 15) * 8;
            const float* src = B + (size_t)(k0 + kr) * N + bn * 128 + nc;
            float4 f0 = *(const float4*)(src);
            float4 f1 = *(const float4*)(src + 4);
            Bs[nc + 0][kr] = f2bs(f0.x); Bs[nc + 1][kr] = f2bs(f0.y);
            Bs[nc + 2][kr] = f2bs(f0.z); Bs[nc + 3][kr] = f2bs(f0.w);
            Bs[nc + 4][kr] = f2bs(f1.x); Bs[nc + 5][kr] = f2bs(f1.y);
            Bs[nc + 6][kr] = f2bs(f1.z); Bs[nc + 7][kr] = f2bs(f1.w);
        }
        __syncthreads();

        s8v a[4], b[4];
#pragma unroll
        for (int i = 0; i < 4; i++) a[i] = *(s8v*)&As[wm * 64 + i * 16 + m16][quad * 8];
#pragma unroll
        for (int j = 0; j < 4; j++) b[j] = *(s8v*)&Bs[wn * 64 + j * 16 + m16][quad * 8];
#pragma unroll
        for (int i = 0; i < 4; i++)
#pragma unroll
            for (int j = 0; j < 4; j++) acc[i][j] = MFMA16(a[i], b[j], acc[i][j]);
        __syncthreads();
    }

#pragma unroll
    for (int i = 0; i < 4; i++)
#pragma unroll
        for (int j = 0; j < 4; j++)
#pragma unroll
            for (int r = 0; r < 4; r++) {
                int row = bm * 128 + wm * 64 + i * 16 + quad * 4 + r;
                int col = bn * 128 + wn * 64 + j * 16 + m16;
                if constexpr (std::is_same<CT, float>::value)
                    C[(size_t)row * N + col] = acc[i][j][r];
                else
                    C[(size_t)row * N + col] = __float2bfloat16(acc[i][j][r]);
            }
}

// ---------------------------------------------------------------------------
// RoPE in-place on bf16 Q and K; freqs fp32.
// ---------------------------------------------------------------------------
__global__ void rope_kernel(bf16* __restrict__ Q, bf16* __restrict__ K,
                            const float* __restrict__ fc, const float* __restrict__ fs) {
    int tid = blockIdx.x * blockDim.x + threadIdx.x;
    int s = tid >> 11;
    int r = tid & 2047;
    int i = r & 63;
    float c  = fc[s * 64 + i];
    float sn = fs[s * 64 + i];
    size_t idx = (size_t)s * DIM + 2 * r;
    float qre = __bfloat162float(Q[idx]), qim = __bfloat162float(Q[idx + 1]);
    Q[idx]     = __float2bfloat16(qre * c - qim * sn);
    Q[idx + 1] = __float2bfloat16(qre * sn + qim * c);
    float kre = __bfloat162float(K[idx]), kim = __bfloat162float(K[idx + 1]);
    K[idx]     = __float2bfloat16(kre * c - kim * sn);
    K[idx + 1] = __float2bfloat16(kre * sn + kim * c);
}

// ---------------------------------------------------------------------------
// Flash attention (causal), PAIRED for load balance.
// Grid: (SEQ/128 = 16 pairs, 32 heads) = 512 UNIFORM blocks (33 iters each):
// block p handles q-tiles p and 31-p sequentially -> no long-block tail,
// constant 2 blocks/CU residency for the whole kernel (was ~1 avg, 11% occ).
// Inner structure unchanged from R1 (coalesced V staging w/ XOR-swizzled
// transpose stores, K/V register prefetch, 2 barriers/iter).
// ---------------------------------------------------------------------------
__global__ __launch_bounds__(256) void attn_kernel(const bf16* __restrict__ Q,
                                                   const bf16* __restrict__ K,
                                                   const bf16* __restrict__ V,
                                                   bf16* __restrict__ O) {
    __shared__ short Ks[64][136];
    __shared__ short Vs[128][72];
    __shared__ short Ps[64][72];

    const int p  = blockIdx.x;            // pair index 0..15
    const int h  = blockIdx.y;
    const int tid  = threadIdx.x;
    const int w    = tid >> 6;
    const int lane = tid & 63;
    const int m16  = lane & 15;
    const int quad = lane >> 4;
    const float scale = 0.08838834764831845f;   // 1/sqrt(128)
    const int NQB = (int)gridDim.x * 2;   // 32 q-tiles

    const int rn  = tid >> 4;            // 0..15
    const int rc  = (tid & 15) * 8;      // 0,8,...,120
    const int dcs = (tid & 15) & 7;      // = (rc>>3)&7, V write swizzle term

    for (int half = 0; half < 2; half++) {
        const int qb = half ? (NQB - 1 - p) : p;

        s8v aq[4];
        {
            const bf16* qp = Q + (size_t)(qb * 64 + w * 16 + m16) * DIM + h * HD + quad * 8;
#pragma unroll
            for (int ks = 0; ks < 4; ks++) aq[ks] = *(const s8v*)(qp + ks * 32);
        }

        f4v acc[8] = {};
        float mrow[4] = {-1e30f, -1e30f, -1e30f, -1e30f};
        float lrow[4] = {};

        // prologue: load tile 0 into regs (coalesced)
        s8v kreg[4], vreg[4];
        {
            const bf16* kp = K + (size_t)rn * DIM + h * HD + rc;
            const bf16* vp = V + (size_t)rn * DIM + h * HD + rc;
#pragma unroll
            for (int it = 0; it < 4; it++) {
                kreg[it] = *(const s8v*)(kp + (size_t)it * 16 * DIM);
                vreg[it] = *(const s8v*)(vp + (size_t)it * 16 * DIM);
            }
        }

        for (int kt = 0; kt <= qb; kt++) {
            // ---- stage regs -> LDS (K direct; V transposed w/ XOR swizzle) ----
#pragma unroll
            for (int it = 0; it < 4; it++)
                *(s8v*)&Ks[it * 16 + rn][rc] = kreg[it];
#pragma unroll
            for (int it = 0; it < 4; it++) {
                int n   = it * 16 + rn;                       // key index 0..63
                int col = (((n >> 3) ^ dcs) << 3) | (n & 7);  // swizzled column
#pragma unroll
                for (int e = 0; e < 8; e++) Vs[rc + e][col] = vreg[it][e];
            }
            __syncthreads();

            // ---- prefetch tile kt+1 ----
            if (kt < qb) {
                const bf16* kp = K + (size_t)((kt + 1) * 64 + rn) * DIM + h * HD + rc;
                const bf16* vp = V + (size_t)((kt + 1) * 64 + rn) * DIM + h * HD + rc;
#pragma unroll
                for (int it = 0; it < 4; it++) {
                    kreg[it] = *(const s8v*)(kp + (size_t)it * 16 * DIM);
                    vreg[it] = *(const s8v*)(vp + (size_t)it * 16 * DIM);
                }
            }

            // ---- QK^T ----
            f4v sc[4] = {};
#pragma unroll
            for (int j = 0; j < 4; j++)
#pragma unroll
                for (int ks = 0; ks < 4; ks++) {
                    s8v bk = *(s8v*)&Ks[j * 16 + m16][ks * 32 + quad * 8];
                    sc[j] = MFMA16(aq[ks], bk, sc[j]);
                }

            const bool diag = (kt == qb);
#pragma unroll
            for (int j = 0; j < 4; j++)
#pragma unroll
                for (int r = 0; r < 4; r++) {
                    float sv = sc[j][r] * scale;
                    if (diag && (j * 16 + m16) > (w * 16 + quad * 4 + r)) sv = -1e30f;
                    sc[j][r] = sv;
                }

            // ---- online softmax ----
#pragma unroll
            for (int r = 0; r < 4; r++) {
                float mx = fmaxf(fmaxf(sc[0][r], sc[1][r]), fmaxf(sc[2][r], sc[3][r]));
#pragma unroll
                for (int off = 1; off < 16; off <<= 1) mx = fmaxf(mx, __shfl_xor(mx, off, 64));
                float mn    = fmaxf(mrow[r], mx);
                float alpha = __expf(mrow[r] - mn);
                mrow[r] = mn;
                float rs = 0.f;
#pragma unroll
                for (int j = 0; j < 4; j++) {
                    float pj = __expf(sc[j][r] - mn);
                    sc[j][r] = pj;
                    rs += pj;
                }
#pragma unroll
                for (int off = 1; off < 16; off <<= 1) rs += __shfl_xor(rs, off, 64);
                lrow[r] = lrow[r] * alpha + rs;
#pragma unroll
                for (int jo = 0; jo < 8; jo++) acc[jo][r] = acc[jo][r] * alpha;
            }

            // ---- P store (wave-private rows -> no block barrier needed) ----
#pragma unroll
            for (int j = 0; j < 4; j++)
#pragma unroll
                for (int r = 0; r < 4; r++)
                    Ps[w * 16 + quad * 4 + r][j * 16 + m16] = f2bs(sc[j][r]);
            asm volatile("s_waitcnt lgkmcnt(0)" ::: "memory");
            __builtin_amdgcn_sched_barrier(0);

            // ---- PV (Vs read through the same XOR swizzle) ----
#pragma unroll
            for (int ks2 = 0; ks2 < 2; ks2++) {
                s8v ap = *(s8v*)&Ps[w * 16 + m16][ks2 * 32 + quad * 8];
#pragma unroll
                for (int jo = 0; jo < 8; jo++) {
                    int dv = jo * 16 + m16;
                    int cg = (((ks2 * 4 + quad) ^ ((dv >> 3) & 7)) << 3);
                    s8v bv = *(s8v*)&Vs[dv][cg];
                    acc[jo] = MFMA16(ap, bv, acc[jo]);
                }
            }
            __syncthreads();
        }

#pragma unroll
        for (int jo = 0; jo < 8; jo++)
#pragma unroll
            for (int r = 0; r < 4; r++) {
                float o = acc[jo][r] / fmaxf(lrow[r], 1e-30f);
                int row = qb * 64 + w * 16 + quad * 4 + r;
                int col = h * HD + jo * 16 + m16;
                O[(size_t)row * DIM + col] = __float2bfloat16(o);
            }
    }
}

// ---------------------------------------------------------------------------
extern "C" void kernel_launch(void* const* d_in, const int* in_sizes, int n_in,
                              void* d_out, int out_size, void* d_ws, size_t ws_size,
                              hipStream_t stream) {
    const float* x  = (const float*)d_in[0];
    const float* wq = (const float*)d_in[1];
    const float* wk = (const float*)d_in[2];
    const float* wv = (const float*)d_in[3];
    const float* wo = (const float*)d_in[4];
    const float* fc = (const float*)d_in[5];
    const float* fs = (const float*)d_in[6];

    float* out = (float*)d_out;

    const size_t SZ = (size_t)SEQ * DIM;
    const size_t WZ = (size_t)DIM * DIM;
    bf16* Q  = (bf16*)d_ws;
    bf16* Kb = Q + SZ;
    bf16* V  = Kb + SZ;
    bf16* AO = V + SZ;

    const size_t need = (5 * SZ + WZ) * sizeof(bf16);   // 112 MB

    if (ws_size >= need) {
        bf16* xb = AO + SZ;        // [SEQ][DIM] bf16
        bf16* wb = xb + SZ;        // [DIM][DIM] bf16, transposed weight, reused

        dim3 tGw(DIM / 64, DIM / 64);
        dim3 gG8(DIM / 256, SEQ / 128);     // (16, 16) = 256 blocks

        convert_bf16<<<(int)(SZ / 4 / 256), 256, 0, stream>>>(x, xb);

        convt_bf16<<<tGw, 256, 0, stream>>>(wq, wb, DIM, DIM);
        gemm_8p<bf16><<<gG8, 512, 0, stream>>>(xb, wb, Q, SEQ, DIM, DIM);
        convt_bf16<<<tGw, 256, 0, stream>>>(wk, wb, DIM, DIM);
        gemm_8p<bf16><<<gG8, 512, 0, stream>>>(xb, wb, Kb, SEQ, DIM, DIM);
        convt_bf16<<<tGw, 256, 0, stream>>>(wv, wb, DIM, DIM);
        gemm_8p<bf16><<<gG8, 512, 0, stream>>>(xb, wb, V, SEQ, DIM, DIM);

        rope_kernel<<<(SEQ * (DIM / 2)) / 256, 256, 0, stream>>>(Q, Kb, fc, fs);
        attn_kernel<<<dim3(SEQ / 128, NH), 256, 0, stream>>>(Q, Kb, V, AO);

        convt_bf16<<<tGw, 256, 0, stream>>>(wo, wb, DIM, DIM);
        gemm_8p<float><<<gG8, 512, 0, stream>>>(AO, wb, out, SEQ, DIM, DIM);
    } else {
        dim3 gGn(DIM / 128, SEQ / 128);
        gemm_nat<float, bf16><<<gGn, 256, 0, stream>>>(x, wq, Q,  SEQ, DIM, DIM);
        gemm_nat<float, bf16><<<gGn, 256, 0, stream>>>(x, wk, Kb, SEQ, DIM, DIM);
        gemm_nat<float, bf16><<<gGn, 256, 0, stream>>>(x, wv, V,  SEQ, DIM, DIM);
        rope_kernel<<<(SEQ * (DIM / 2)) / 256, 256, 0, stream>>>(Q, Kb, fc, fs);
        attn_kernel<<<dim3(SEQ / 128, NH), 256, 0, stream>>>(Q, Kb, V, AO);
        gemm_nat<bf16, float><<<gGn, 256, 0, stream>>>(AO, wo, out, SEQ, DIM, DIM);
    }
}